// Round 10
// baseline (60.645 us; speedup 1.0000x reference)
//
#include <hip/hip_runtime.h>
#include <math.h>

typedef _Float16 f16;
typedef _Float16 f16x8 __attribute__((ext_vector_type(8)));
typedef float f32x16 __attribute__((ext_vector_type(16)));

#define TPB 256
#define RB 2                        // 32-row MFMA blocks per wave
#define ROWS_PER_BLOCK (4*RB*32)    // 256 rows per block (4 waves)
#define CC 512                      // T-points (cols) per block (16 KB LDS)

static __device__ __forceinline__ unsigned pk(f16 a, f16 b) {
    union { f16 h[2]; unsigned u; } v; v.h[0] = a; v.h[1] = b; return v.u;
}

// Encode points so that enc_row(p) . enc_col(t) = |p|^2 + |t|^2 - 2 p.t = d^2
// to ~4e-5 (hi/lo f16 split; verified r8/r9: absmax 0.0). Single-pass dual
// direction needs only Prow (P as rows) and Tcol (T as cols).
// Also initializes gmin[NP+NT] and *out (replaces memset dispatches).
__global__ __launch_bounds__(TPB) void chamfer_encode(
    const float* __restrict__ P, int NP, const float* __restrict__ T, int NT,
    ushort* __restrict__ Prow, ushort* __restrict__ Tcol,
    unsigned* __restrict__ gminF, float* __restrict__ out)
{
    const int i = blockIdx.x * TPB + threadIdx.x;
    if (i >= NP + NT) return;
    gminF[i] = 0xFFFFFFFFu;               // gminF and gminB are contiguous
    if (i == 0) *out = 0.f;

    const float x = (i < NP) ? P[3*i]   : T[3*(i-NP)];
    const float y = (i < NP) ? P[3*i+1] : T[3*(i-NP)+1];
    const float z = (i < NP) ? P[3*i+2] : T[3*(i-NP)+2];
    const float s2 = x*x + y*y + z*z;

    const f16 xh = (f16)x,  xl = (f16)(x - (float)xh);
    const f16 yh = (f16)y,  yl = (f16)(y - (float)yh);
    const f16 zh = (f16)z,  zl = (f16)(z - (float)zh);
    const f16 sh = (f16)s2, sl = (f16)(s2 - (float)sh);
    const f16 one = (f16)1.f, zer = (f16)0.f;

    if (i < NP) {
        const float ux = -2.f*x, uy = -2.f*y, uz = -2.f*z;
        const f16 uxh = (f16)ux, uxl = (f16)(ux - (float)uxh);
        const f16 uyh = (f16)uy, uyl = (f16)(uy - (float)uyh);
        const f16 uzh = (f16)uz, uzl = (f16)(uz - (float)uzh);
        // row enc: [uxh,uxl,uxh, uyh,uyl,uyh, uzh,uzl,uzh, sh,sl, 1,1, 0,0,0]
        uint4 r0 = { pk(uxh,uxl), pk(uxh,uyh), pk(uyl,uyh), pk(uzh,uzl) };
        uint4 r1 = { pk(uzh,sh),  pk(sl,one),  pk(one,zer), pk(zer,zer) };
        *(uint4*)(Prow + (size_t)i*16)     = r0;
        *(uint4*)(Prow + (size_t)i*16 + 8) = r1;
    } else {
        const int j = i - NP;
        // col enc: [xh,xh,xl, yh,yh,yl, zh,zh,zl, 1,1, sh,sl, 0,0,0]
        uint4 c0 = { pk(xh,xh), pk(xl,yh), pk(yh,yl), pk(zh,zh) };
        uint4 c1 = { pk(zl,one), pk(one,sh), pk(sl,zer), pk(zer,zer) };
        *(uint4*)(Tcol + (size_t)j*16)     = c0;
        *(uint4*)(Tcol + (size_t)j*16 + 8) = c1;
    }
}

// Single pass, dual direction: each 32x32 d^2 tile feeds BOTH row-min
// (forward, running regs) and col-min (backward, in-lane tree -> LDS
// atomicMin -> global). C-layout (verified r8/r9): col=lane&31,
// row=(reg&3)+8*(reg>>2)+4*(lane>>5) -- a lane's 16 regs are 16 distinct
// rows of ONE column, so col-min = in-lane tree + shfl_xor(32).
// Pressure discipline (r9 lesson: >110 live acc regs -> tuple copies +
// kZero remat = ~100 VALU/MFMA): exactly ONE f32x16 MFMA result live at a
// time, unroll 1, no launch_bounds cap (r4/r6/r7 spills).
__global__ __launch_bounds__(TPB) void chamfer_mfma(
    const ushort* __restrict__ Prow, int NP,
    const ushort* __restrict__ Tcol, int NT,
    unsigned* __restrict__ gminF, unsigned* __restrict__ gminB)
{
    const int rowbase = blockIdx.x * ROWS_PER_BLOCK;
    const int col0 = blockIdx.y * CC;
    if (rowbase >= NP || col0 >= NT) return;

    __shared__ alignas(16) ushort Alds[2 * ROWS_PER_BLOCK * 8]; // 8 KB [kg][row][8]
    __shared__ alignas(16) ushort Blds[2 * CC * 8];             // 16 KB [kg][col][8]
    __shared__ unsigned colmin[CC];                              // 2 KB

    const int tid = threadIdx.x;
    {   // stage A rows (one 32B enc per thread, split by k-half)
        const int r = min(rowbase + tid, NP - 1);
        const uint4* s = (const uint4*)(Prow + (size_t)r * 16);
        *(uint4*)(Alds + tid * 8)                    = s[0];
        *(uint4*)(Alds + (ROWS_PER_BLOCK + tid) * 8) = s[1];
    }
    for (int t = tid; t < CC; t += TPB) {   // stage B cols + init colmin
        const int c = min(col0 + t, NT - 1);
        const uint4* s = (const uint4*)(Tcol + (size_t)c * 16);
        *(uint4*)(Blds + t * 8)        = s[0];
        *(uint4*)(Blds + (CC + t) * 8) = s[1];
        colmin[t] = 0xFFFFFFFFu;
    }
    __syncthreads();

    const int l = tid & 63, w = tid >> 6;
    const int kg = l >> 5;     // k-half this lane feeds
    const int ln = l & 31;     // col (B) / row (A) index within 32-tile

    f16x8 af0, af1;
    {
        const int row0 = (w * RB + 0) * 32 + ln;
        const int row1 = (w * RB + 1) * 32 + ln;
        af0 = *(const f16x8*)(Alds + (kg * ROWS_PER_BLOCK + row0) * 8);
        af1 = *(const f16x8*)(Alds + (kg * ROWS_PER_BLOCK + row1) * 8);
    }

    const f32x16 kZero = {0,0,0,0,0,0,0,0,0,0,0,0,0,0,0,0};
    f32x16 mr0, mr1;
#pragma unroll
    for (int r = 0; r < 16; r++) { mr0[r] = 3.4e38f; mr1[r] = 3.4e38f; }

    const ushort* Bk = Blds + kg * CC * 8;
#pragma unroll 1
    for (int cb = 0; cb < CC / 32; ++cb) {
        const f16x8 bf = *(const f16x8*)(Bk + (cb * 32 + ln) * 8);

        float cm;
        {   // tile rb0: rows w*64..w*64+31
            f32x16 d = __builtin_amdgcn_mfma_f32_32x32x16_f16(af0, bf, kZero, 0, 0, 0);
#pragma unroll
            for (int r = 0; r < 16; r++) mr0[r] = fminf(mr0[r], d[r]);
            // in-lane col tree (16 rows of col ln)
            float t0 = fminf(fminf(d[0], d[1]),  fminf(d[2], d[3]));
            float t1 = fminf(fminf(d[4], d[5]),  fminf(d[6], d[7]));
            float t2 = fminf(fminf(d[8], d[9]),  fminf(d[10], d[11]));
            float t3 = fminf(fminf(d[12], d[13]), fminf(d[14], d[15]));
            cm = fminf(fminf(t0, t1), fminf(t2, t3));
        }
        {   // tile rb1: rows w*64+32..w*64+63  (d0 dead before d1 issues)
            f32x16 d = __builtin_amdgcn_mfma_f32_32x32x16_f16(af1, bf, kZero, 0, 0, 0);
#pragma unroll
            for (int r = 0; r < 16; r++) mr1[r] = fminf(mr1[r], d[r]);
            float t0 = fminf(fminf(d[0], d[1]),  fminf(d[2], d[3]));
            float t1 = fminf(fminf(d[4], d[5]),  fminf(d[6], d[7]));
            float t2 = fminf(fminf(d[8], d[9]),  fminf(d[10], d[11]));
            float t3 = fminf(fminf(d[12], d[13]), fminf(d[14], d[15]));
            cm = fminf(cm, fminf(fminf(t0, t1), fminf(t2, t3)));
        }
        // combine the other kg's 32 rows (lane^32 has same col, other rows)
        cm = fminf(cm, __shfl_xor(cm, 32));
        if (kg == 0)
            atomicMin(&colmin[cb * 32 + ln], __float_as_uint(fmaxf(cm, 0.f)));
    }

    // forward: reduce row-min over the 32 cols, one atomicMin per row
#pragma unroll
    for (int rb = 0; rb < RB; rb++) {
#pragma unroll
        for (int r = 0; r < 16; r++) {
            float v = rb ? mr1[r] : mr0[r];
            v = fminf(v, __shfl_xor(v, 1));
            v = fminf(v, __shfl_xor(v, 2));
            v = fminf(v, __shfl_xor(v, 4));
            v = fminf(v, __shfl_xor(v, 8));
            v = fminf(v, __shfl_xor(v, 16));
            if (ln == 0) {
                const int row = rowbase + (w * RB + rb) * 32 + (r & 3) + 8 * (r >> 2) + 4 * kg;
                if (row < NP)
                    atomicMin(&gminF[row], __float_as_uint(fmaxf(v, 0.f)));
            }
        }
    }

    // backward: flush block's col-mins to global
    __syncthreads();
    for (int t = tid; t < CC; t += TPB) {
        const int c = min(col0 + t, NT - 1);
        atomicMin(&gminB[c], colmin[t]);
    }
}

// gmin bits -> sqrt -> scaled sum into *out.
__global__ __launch_bounds__(TPB) void chamfer_final(
    const unsigned* __restrict__ gminF, int NP,
    const unsigned* __restrict__ gminB, int NT,
    float scaleF, float scaleB, float* __restrict__ out)
{
    const int gid = blockIdx.x * TPB + threadIdx.x;
    float val = 0.f;
    if (gid < NP) {
        val = sqrtf(fmaxf(__uint_as_float(gminF[gid]), 0.f)) * scaleF;
    } else if (gid < NP + NT) {
        val = sqrtf(fmaxf(__uint_as_float(gminB[gid - NP]), 0.f)) * scaleB;
    }
#pragma unroll
    for (int off = 32; off > 0; off >>= 1) val += __shfl_down(val, off);
    __shared__ float red[TPB / 64];
    const int lane = threadIdx.x & 63;
    const int w = threadIdx.x >> 6;
    if (lane == 0) red[w] = val;
    __syncthreads();
    if (threadIdx.x == 0) {
        float s = 0.f;
#pragma unroll
        for (int i = 0; i < TPB / 64; i++) s += red[i];
        atomicAdd(out, s);
    }
}

extern "C" void kernel_launch(void* const* d_in, const int* in_sizes, int n_in,
                              void* d_out, int out_size, void* d_ws, size_t ws_size,
                              hipStream_t stream) {
    const float* P = (const float*)d_in[0];
    const float* T = (const float*)d_in[1];
    const int NP = in_sizes[0] / 3;
    const int NT = in_sizes[1] / 3;
    float* out = (float*)d_out;

    unsigned* gminF = (unsigned*)d_ws;
    unsigned* gminB = gminF + NP;
    ushort* Prow = (ushort*)(gminB + NT);
    ushort* Tcol = Prow + (size_t)NP * 16;
    // ws usage: (NP+NT)*4 + (NP+NT)*32 bytes ~= 1.2 MB

    const int eblocks = (NP + NT + TPB - 1) / TPB;
    chamfer_encode<<<eblocks, TPB, 0, stream>>>(P, NP, T, NT, Prow, Tcol, gminF, out);

    dim3 grid((NP + ROWS_PER_BLOCK - 1) / ROWS_PER_BLOCK,
              (NT + CC - 1) / CC, 1);
    chamfer_mfma<<<grid, TPB, 0, stream>>>(Prow, NP, Tcol, NT, gminF, gminB);

    const int fblocks = (NP + NT + TPB - 1) / TPB;
    chamfer_final<<<fblocks, TPB, 0, stream>>>(gminF, NP, gminB, NT,
                                               1.0f / (float)NP, 1.0f / (float)NT, out);
}

// Round 11
// 57.358 us; speedup vs baseline: 1.0573x; 1.0573x over previous
//
#include <hip/hip_runtime.h>
#include <math.h>

typedef _Float16 f16;
typedef _Float16 f16x8 __attribute__((ext_vector_type(8)));
typedef float f32x16 __attribute__((ext_vector_type(16)));

#define TPB 256
#define RB 2                        // 32-row MFMA blocks per wave
#define ROWS_PER_BLOCK (4*RB*32)    // 256 rows per block (4 waves)
#define CC 512                      // T-points (cols) per block (16 KB LDS)

static __device__ __forceinline__ unsigned pk(f16 a, f16 b) {
    union { f16 h[2]; unsigned u; } v; v.h[0] = a; v.h[1] = b; return v.u;
}

// Encode points so that enc_row(p) . enc_col(t) = |p|^2 + |t|^2 - 2 p.t = d^2
// to ~4e-5 (hi/lo f16 split; verified r8-r10: absmax 0.0). Single-pass dual
// direction needs only Prow (P as rows) and Tcol (T as cols).
// Also initializes gmin[NP+NT] and *out (replaces memset dispatches).
__global__ __launch_bounds__(TPB) void chamfer_encode(
    const float* __restrict__ P, int NP, const float* __restrict__ T, int NT,
    ushort* __restrict__ Prow, ushort* __restrict__ Tcol,
    unsigned* __restrict__ gminF, float* __restrict__ out)
{
    const int i = blockIdx.x * TPB + threadIdx.x;
    if (i >= NP + NT) return;
    gminF[i] = 0xFFFFFFFFu;               // gminF and gminB are contiguous
    if (i == 0) *out = 0.f;

    const float x = (i < NP) ? P[3*i]   : T[3*(i-NP)];
    const float y = (i < NP) ? P[3*i+1] : T[3*(i-NP)+1];
    const float z = (i < NP) ? P[3*i+2] : T[3*(i-NP)+2];
    const float s2 = x*x + y*y + z*z;

    const f16 xh = (f16)x,  xl = (f16)(x - (float)xh);
    const f16 yh = (f16)y,  yl = (f16)(y - (float)yh);
    const f16 zh = (f16)z,  zl = (f16)(z - (float)zh);
    const f16 sh = (f16)s2, sl = (f16)(s2 - (float)sh);
    const f16 one = (f16)1.f, zer = (f16)0.f;

    if (i < NP) {
        const float ux = -2.f*x, uy = -2.f*y, uz = -2.f*z;
        const f16 uxh = (f16)ux, uxl = (f16)(ux - (float)uxh);
        const f16 uyh = (f16)uy, uyl = (f16)(uy - (float)uyh);
        const f16 uzh = (f16)uz, uzl = (f16)(uz - (float)uzh);
        // row enc: [uxh,uxl,uxh, uyh,uyl,uyh, uzh,uzl,uzh, sh,sl, 1,1, 0,0,0]
        uint4 r0 = { pk(uxh,uxl), pk(uxh,uyh), pk(uyl,uyh), pk(uzh,uzl) };
        uint4 r1 = { pk(uzh,sh),  pk(sl,one),  pk(one,zer), pk(zer,zer) };
        *(uint4*)(Prow + (size_t)i*16)     = r0;
        *(uint4*)(Prow + (size_t)i*16 + 8) = r1;
    } else {
        const int j = i - NP;
        // col enc: [xh,xh,xl, yh,yh,yl, zh,zh,zl, 1,1, sh,sl, 0,0,0]
        uint4 c0 = { pk(xh,xh), pk(xl,yh), pk(yh,yl), pk(zh,zh) };
        uint4 c1 = { pk(zl,one), pk(one,sh), pk(sl,zer), pk(zer,zer) };
        *(uint4*)(Tcol + (size_t)j*16)     = c0;
        *(uint4*)(Tcol + (size_t)j*16 + 8) = c1;
    }
}

// Single pass, dual direction: each 32x32 d^2 tile feeds BOTH row-min
// (forward, running regs) and col-min (backward, in-lane min3 tree -> LDS
// atomicMin -> global). C-layout (verified r8-r10): col=lane&31,
// row=(reg&3)+8*(reg>>2)+4*(lane>>5).
//
// REGISTER-FORM DISCIPLINE (r10 lesson): with no launch_bounds the compiler
// targets max occupancy (~64 VGPR budget) and allocates all MFMA accs in
// AGPRs -> every fmin on them pays v_accvgpr_read/write (3-4 VALU per source
// fmin; r10: VGPR_Count=52, VALU busy 39us vs ~8us source-level, occupancy
// 33% from hidden AGPRs). (256,4) = 128-VGPR budget fits the ~104 live set
// entirely in VGPRs. r4's disaster was a cap BELOW the live set (64 < 90).
__global__ __launch_bounds__(TPB, 4) void chamfer_mfma(
    const ushort* __restrict__ Prow, int NP,
    const ushort* __restrict__ Tcol, int NT,
    unsigned* __restrict__ gminF, unsigned* __restrict__ gminB)
{
    const int rowbase = blockIdx.x * ROWS_PER_BLOCK;
    const int col0 = blockIdx.y * CC;
    if (rowbase >= NP || col0 >= NT) return;

    __shared__ alignas(16) ushort Alds[2 * ROWS_PER_BLOCK * 8]; // 8 KB [kg][row][8]
    __shared__ alignas(16) ushort Blds[2 * CC * 8];             // 16 KB [kg][col][8]
    __shared__ unsigned colmin[CC];                              // 2 KB

    const int tid = threadIdx.x;
    {   // stage A rows (one 32B enc per thread, split by k-half)
        const int r = min(rowbase + tid, NP - 1);
        const uint4* s = (const uint4*)(Prow + (size_t)r * 16);
        *(uint4*)(Alds + tid * 8)                    = s[0];
        *(uint4*)(Alds + (ROWS_PER_BLOCK + tid) * 8) = s[1];
    }
    for (int t = tid; t < CC; t += TPB) {   // stage B cols + init colmin
        const int c = min(col0 + t, NT - 1);
        const uint4* s = (const uint4*)(Tcol + (size_t)c * 16);
        *(uint4*)(Blds + t * 8)        = s[0];
        *(uint4*)(Blds + (CC + t) * 8) = s[1];
        colmin[t] = 0xFFFFFFFFu;
    }
    __syncthreads();

    const int l = tid & 63, w = tid >> 6;
    const int kg = l >> 5;     // k-half this lane feeds
    const int ln = l & 31;     // col (B) / row (A) index within 32-tile

    f16x8 af0, af1;
    {
        const int row0 = (w * RB + 0) * 32 + ln;
        const int row1 = (w * RB + 1) * 32 + ln;
        af0 = *(const f16x8*)(Alds + (kg * ROWS_PER_BLOCK + row0) * 8);
        af1 = *(const f16x8*)(Alds + (kg * ROWS_PER_BLOCK + row1) * 8);
    }

    const f32x16 kZero = {0,0,0,0,0,0,0,0,0,0,0,0,0,0,0,0};
    f32x16 mr0, mr1;
#pragma unroll
    for (int r = 0; r < 16; r++) { mr0[r] = 3.4e38f; mr1[r] = 3.4e38f; }

    const ushort* Bk = Blds + kg * CC * 8;
#pragma unroll 1
    for (int cb = 0; cb < CC / 32; ++cb) {
        const f16x8 bf = *(const f16x8*)(Bk + (cb * 32 + ln) * 8);

        float cm;
        {   // tile rb0: rows w*64..w*64+31
            f32x16 d = __builtin_amdgcn_mfma_f32_32x32x16_f16(af0, bf, kZero, 0, 0, 0);
#pragma unroll
            for (int r = 0; r < 16; r++) mr0[r] = fminf(mr0[r], d[r]);
            // in-lane col tree, min3-nested (16 -> 1 in ~8 ops)
            const float u0 = fminf(fminf(d[0],  d[1]),  d[2]);
            const float u1 = fminf(fminf(d[3],  d[4]),  d[5]);
            const float u2 = fminf(fminf(d[6],  d[7]),  d[8]);
            const float u3 = fminf(fminf(d[9],  d[10]), d[11]);
            const float u4 = fminf(fminf(d[12], d[13]), d[14]);
            const float u5 = fminf(fminf(u0, u1), d[15]);
            cm = fminf(fminf(fminf(u2, u3), u4), u5);
        }
        {   // tile rb1: rows w*64+32..w*64+63 (d0 dead before d1 issues)
            f32x16 d = __builtin_amdgcn_mfma_f32_32x32x16_f16(af1, bf, kZero, 0, 0, 0);
#pragma unroll
            for (int r = 0; r < 16; r++) mr1[r] = fminf(mr1[r], d[r]);
            const float u0 = fminf(fminf(d[0],  d[1]),  d[2]);
            const float u1 = fminf(fminf(d[3],  d[4]),  d[5]);
            const float u2 = fminf(fminf(d[6],  d[7]),  d[8]);
            const float u3 = fminf(fminf(d[9],  d[10]), d[11]);
            const float u4 = fminf(fminf(d[12], d[13]), d[14]);
            const float u5 = fminf(fminf(u0, u1), d[15]);
            cm = fminf(cm, fminf(fminf(fminf(u2, u3), u4), u5));
        }
        // combine the other kg's 32 rows (lane^32 has same col, other rows)
        cm = fminf(cm, __shfl_xor(cm, 32));
        if (kg == 0)
            atomicMin(&colmin[cb * 32 + ln], __float_as_uint(fmaxf(cm, 0.f)));
    }

    // forward: reduce row-min over the 32 cols, one atomicMin per row
#pragma unroll
    for (int rb = 0; rb < RB; rb++) {
#pragma unroll
        for (int r = 0; r < 16; r++) {
            float v = rb ? mr1[r] : mr0[r];
            v = fminf(v, __shfl_xor(v, 1));
            v = fminf(v, __shfl_xor(v, 2));
            v = fminf(v, __shfl_xor(v, 4));
            v = fminf(v, __shfl_xor(v, 8));
            v = fminf(v, __shfl_xor(v, 16));
            if (ln == 0) {
                const int row = rowbase + (w * RB + rb) * 32 + (r & 3) + 8 * (r >> 2) + 4 * kg;
                if (row < NP)
                    atomicMin(&gminF[row], __float_as_uint(fmaxf(v, 0.f)));
            }
        }
    }

    // backward: flush block's col-mins to global
    __syncthreads();
    for (int t = tid; t < CC; t += TPB) {
        const int c = min(col0 + t, NT - 1);
        atomicMin(&gminB[c], colmin[t]);
    }
}

// gmin bits -> sqrt -> scaled sum into *out.
__global__ __launch_bounds__(TPB) void chamfer_final(
    const unsigned* __restrict__ gminF, int NP,
    const unsigned* __restrict__ gminB, int NT,
    float scaleF, float scaleB, float* __restrict__ out)
{
    const int gid = blockIdx.x * TPB + threadIdx.x;
    float val = 0.f;
    if (gid < NP) {
        val = sqrtf(fmaxf(__uint_as_float(gminF[gid]), 0.f)) * scaleF;
    } else if (gid < NP + NT) {
        val = sqrtf(fmaxf(__uint_as_float(gminB[gid - NP]), 0.f)) * scaleB;
    }
#pragma unroll
    for (int off = 32; off > 0; off >>= 1) val += __shfl_down(val, off);
    __shared__ float red[TPB / 64];
    const int lane = threadIdx.x & 63;
    const int w = threadIdx.x >> 6;
    if (lane == 0) red[w] = val;
    __syncthreads();
    if (threadIdx.x == 0) {
        float s = 0.f;
#pragma unroll
        for (int i = 0; i < TPB / 64; i++) s += red[i];
        atomicAdd(out, s);
    }
}

extern "C" void kernel_launch(void* const* d_in, const int* in_sizes, int n_in,
                              void* d_out, int out_size, void* d_ws, size_t ws_size,
                              hipStream_t stream) {
    const float* P = (const float*)d_in[0];
    const float* T = (const float*)d_in[1];
    const int NP = in_sizes[0] / 3;
    const int NT = in_sizes[1] / 3;
    float* out = (float*)d_out;

    unsigned* gminF = (unsigned*)d_ws;
    unsigned* gminB = gminF + NP;
    ushort* Prow = (ushort*)(gminB + NT);
    ushort* Tcol = Prow + (size_t)NP * 16;
    // ws usage: (NP+NT)*4 + (NP+NT)*32 bytes ~= 1.2 MB

    const int eblocks = (NP + NT + TPB - 1) / TPB;
    chamfer_encode<<<eblocks, TPB, 0, stream>>>(P, NP, T, NT, Prow, Tcol, gminF, out);

    dim3 grid((NP + ROWS_PER_BLOCK - 1) / ROWS_PER_BLOCK,
              (NT + CC - 1) / CC, 1);
    chamfer_mfma<<<grid, TPB, 0, stream>>>(Prow, NP, Tcol, NT, gminF, gminB);

    const int fblocks = (NP + NT + TPB - 1) / TPB;
    chamfer_final<<<fblocks, TPB, 0, stream>>>(gminF, NP, gminB, NT,
                                               1.0f / (float)NP, 1.0f / (float)NT, out);
}

// Round 12
// 42.816 us; speedup vs baseline: 1.4164x; 1.3397x over previous
//
#include <hip/hip_runtime.h>
#include <math.h>

typedef _Float16 f16;
typedef _Float16 f16x8 __attribute__((ext_vector_type(8)));
typedef float f32x16 __attribute__((ext_vector_type(16)));

#define TPB 256
#define ROWS_PER_BLOCK 256          // 4 waves x 2 rb x 32 rows
#define CC 512                      // T-points (cols) per block

static __device__ __forceinline__ unsigned pk(f16 a, f16 b) {
    union { f16 h[2]; unsigned u; } v; v.h[0] = a; v.h[1] = b; return v.u;
}

// min of 16 f32 (min3-friendly nesting)
static __device__ __forceinline__ float min16(const f32x16& d) {
    const float u0 = fminf(fminf(d[0],  d[1]),  d[2]);
    const float u1 = fminf(fminf(d[3],  d[4]),  d[5]);
    const float u2 = fminf(fminf(d[6],  d[7]),  d[8]);
    const float u3 = fminf(fminf(d[9],  d[10]), d[11]);
    const float u4 = fminf(fminf(d[12], d[13]), d[14]);
    const float u5 = fminf(fminf(u0, u1), d[15]);
    return fminf(fminf(fminf(u2, u3), u4), u5);
}

// Encode points so that enc_row(p) . enc_col(t) = |p|^2 + |t|^2 - 2 p.t = d^2
// to ~4e-5 (hi/lo f16 split; verified r8-r11: absmax 0.0).
// Also initializes gmin[NP+NT] and *out (replaces memset dispatches).
__global__ __launch_bounds__(TPB) void chamfer_encode(
    const float* __restrict__ P, int NP, const float* __restrict__ T, int NT,
    ushort* __restrict__ Prow, ushort* __restrict__ Tcol,
    unsigned* __restrict__ gminF, float* __restrict__ out)
{
    const int i = blockIdx.x * TPB + threadIdx.x;
    if (i >= NP + NT) return;
    gminF[i] = 0xFFFFFFFFu;               // gminF and gminB are contiguous
    if (i == 0) *out = 0.f;

    const float x = (i < NP) ? P[3*i]   : T[3*(i-NP)];
    const float y = (i < NP) ? P[3*i+1] : T[3*(i-NP)+1];
    const float z = (i < NP) ? P[3*i+2] : T[3*(i-NP)+2];
    const float s2 = x*x + y*y + z*z;

    const f16 xh = (f16)x,  xl = (f16)(x - (float)xh);
    const f16 yh = (f16)y,  yl = (f16)(y - (float)yh);
    const f16 zh = (f16)z,  zl = (f16)(z - (float)zh);
    const f16 sh = (f16)s2, sl = (f16)(s2 - (float)sh);
    const f16 one = (f16)1.f, zer = (f16)0.f;

    if (i < NP) {
        const float ux = -2.f*x, uy = -2.f*y, uz = -2.f*z;
        const f16 uxh = (f16)ux, uxl = (f16)(ux - (float)uxh);
        const f16 uyh = (f16)uy, uyl = (f16)(uy - (float)uyh);
        const f16 uzh = (f16)uz, uzl = (f16)(uz - (float)uzh);
        // row enc: [uxh,uxl,uxh, uyh,uyl,uyh, uzh,uzl,uzh, sh,sl, 1,1, 0,0,0]
        uint4 r0 = { pk(uxh,uxl), pk(uxh,uyh), pk(uyl,uyh), pk(uzh,uzl) };
        uint4 r1 = { pk(uzh,sh),  pk(sl,one),  pk(one,zer), pk(zer,zer) };
        *(uint4*)(Prow + (size_t)i*16)     = r0;
        *(uint4*)(Prow + (size_t)i*16 + 8) = r1;
    } else {
        const int j = i - NP;
        // col enc: [xh,xh,xl, yh,yh,yl, zh,zh,zl, 1,1, sh,sl, 0,0,0]
        uint4 c0 = { pk(xh,xh), pk(xl,yh), pk(yh,yl), pk(zh,zh) };
        uint4 c1 = { pk(zl,one), pk(one,sh), pk(sl,zer), pk(zer,zer) };
        *(uint4*)(Tcol + (size_t)j*16)     = c0;
        *(uint4*)(Tcol + (size_t)j*16 + 8) = c1;
    }
}

// Single pass, dual direction. C-layout (verified r8-r11): col=lane&31,
// row=(reg&3)+8*(reg>>2)+4*(lane>>5).
//
// VGPR-FORM VIA INLINE ASM (r10/r11 lesson): builtin MFMA + any
// launch_bounds still allocates accumulators in AGPRs (r11: VGPR_Count=44,
// can't hold the 80-f32 acc set; every fmin pays v_accvgpr_read/write ->
// 31.5us issued-VALU vs ~6us source-level). asm "v" constraints force
// arch-VGPR D/A/B/C -- no AGPR exists in this kernel. MFMA->VALU RAW
// hazard is covered by s_nop 7 x4 (32 cyc) inside the asm (over-padded;
// absmax refcheck guards correctness).
__global__ __launch_bounds__(TPB, 4) void chamfer_mfma(
    const ushort* __restrict__ Prow, int NP,
    const ushort* __restrict__ Tcol, int NT,
    unsigned* __restrict__ gminF, unsigned* __restrict__ gminB)
{
    const int rowbase = blockIdx.x * ROWS_PER_BLOCK;
    const int col0 = blockIdx.y * CC;
    if (rowbase >= NP || col0 >= NT) return;

    __shared__ alignas(16) ushort Blds[2 * CC * 8];  // 16 KB [kg][col][8]
    __shared__ float colw[2][4][CC];                 // 16 KB [kg][wave][col]

    const int tid = threadIdx.x;
    for (int t = tid; t < CC; t += TPB) {   // stage B cols, split by k-half
        const int c = min(col0 + t, NT - 1);
        const uint4* s = (const uint4*)(Tcol + (size_t)c * 16);
        *(uint4*)(Blds + t * 8)        = s[0];
        *(uint4*)(Blds + (CC + t) * 8) = s[1];
    }
    __syncthreads();

    const int l = tid & 63, w = tid >> 6;
    const int kg = l >> 5;     // k-half this lane feeds
    const int ln = l & 31;     // col (B) / row (A) index within 32-tile

    // A fragments straight from global (coalesced 16B/lane; L2-resident)
    const int r0 = min(rowbase + (w * 2 + 0) * 32 + ln, NP - 1);
    const int r1 = min(rowbase + (w * 2 + 1) * 32 + ln, NP - 1);
    const f16x8 af0 = *(const f16x8*)(Prow + (size_t)r0 * 16 + kg * 8);
    const f16x8 af1 = *(const f16x8*)(Prow + (size_t)r1 * 16 + kg * 8);

    f32x16 z, mr0, mr1;
#pragma unroll
    for (int r = 0; r < 16; r++) { z[r] = 0.f; mr0[r] = 3.4e38f; mr1[r] = 3.4e38f; }

    const ushort* Bk = Blds + kg * CC * 8;
#pragma unroll 1
    for (int cb = 0; cb < CC / 32; cb += 2) {
        const f16x8 bf0 = *(const f16x8*)(Bk + (cb * 32 + ln) * 8);
        const f16x8 bf1 = *(const f16x8*)(Bk + ((cb + 1) * 32 + ln) * 8);

        f32x16 d0, d1;
        asm volatile(
            "v_mfma_f32_32x32x16_f16 %0, %2, %3, %5\n\t"
            "v_mfma_f32_32x32x16_f16 %1, %2, %4, %5\n\t"
            "s_nop 7\n\ts_nop 7\n\ts_nop 7\n\ts_nop 7"
            : "=&v"(d0), "=&v"(d1)
            : "v"(af0), "v"(bf0), "v"(bf1), "v"(z));
        float c0 = min16(d0);           // col cb*32+ln, rows rb0 (this kg's 16)
        float c1 = min16(d1);           // col (cb+1)*32+ln
#pragma unroll
        for (int r = 0; r < 16; r++)
            mr0[r] = fminf(mr0[r], fminf(d0[r], d1[r]));   // -> v_min3_f32

        asm volatile(
            "v_mfma_f32_32x32x16_f16 %0, %2, %3, %5\n\t"
            "v_mfma_f32_32x32x16_f16 %1, %2, %4, %5\n\t"
            "s_nop 7\n\ts_nop 7\n\ts_nop 7\n\ts_nop 7"
            : "=&v"(d0), "=&v"(d1)
            : "v"(af1), "v"(bf0), "v"(bf1), "v"(z));
        c0 = fminf(c0, min16(d0));
        c1 = fminf(c1, min16(d1));
#pragma unroll
        for (int r = 0; r < 16; r++)
            mr1[r] = fminf(mr1[r], fminf(d0[r], d1[r]));

        // each wave visits each column exactly once -> plain writes, no atomics
        colw[kg][w][cb * 32 + ln]       = c0;
        colw[kg][w][(cb + 1) * 32 + ln] = c1;
    }

    // forward: reduce row-min over the 32 cols, one atomicMin per row
#pragma unroll
    for (int rb = 0; rb < 2; rb++) {
#pragma unroll
        for (int r = 0; r < 16; r++) {
            float v = rb ? mr1[r] : mr0[r];
            v = fminf(v, __shfl_xor(v, 1));
            v = fminf(v, __shfl_xor(v, 2));
            v = fminf(v, __shfl_xor(v, 4));
            v = fminf(v, __shfl_xor(v, 8));
            v = fminf(v, __shfl_xor(v, 16));
            if (ln == 0) {
                const int row = rowbase + (w * 2 + rb) * 32 + (r & 3) + 8 * (r >> 2) + 4 * kg;
                if (row < NP)
                    atomicMin(&gminF[row], __float_as_uint(fmaxf(v, 0.f)));
            }
        }
    }

    // backward: fold the 8 per-(kg,wave) planes, one global atomic per col
    __syncthreads();
    for (int t = tid; t < CC; t += TPB) {
        const int c = col0 + t;
        if (c >= NT) break;
        float v = colw[0][0][t];
#pragma unroll
        for (int g = 0; g < 2; g++)
#pragma unroll
            for (int ww = 0; ww < 4; ww++)
                if (g | ww) v = fminf(v, colw[g][ww][t]);
        atomicMin(&gminB[c], __float_as_uint(fmaxf(v, 0.f)));
    }
}

// gmin bits -> sqrt -> scaled sum into *out.
__global__ __launch_bounds__(TPB) void chamfer_final(
    const unsigned* __restrict__ gminF, int NP,
    const unsigned* __restrict__ gminB, int NT,
    float scaleF, float scaleB, float* __restrict__ out)
{
    const int gid = blockIdx.x * TPB + threadIdx.x;
    float val = 0.f;
    if (gid < NP) {
        val = sqrtf(fmaxf(__uint_as_float(gminF[gid]), 0.f)) * scaleF;
    } else if (gid < NP + NT) {
        val = sqrtf(fmaxf(__uint_as_float(gminB[gid - NP]), 0.f)) * scaleB;
    }
#pragma unroll
    for (int off = 32; off > 0; off >>= 1) val += __shfl_down(val, off);
    __shared__ float red[TPB / 64];
    const int lane = threadIdx.x & 63;
    const int w = threadIdx.x >> 6;
    if (lane == 0) red[w] = val;
    __syncthreads();
    if (threadIdx.x == 0) {
        float s = 0.f;
#pragma unroll
        for (int i = 0; i < TPB / 64; i++) s += red[i];
        atomicAdd(out, s);
    }
}

extern "C" void kernel_launch(void* const* d_in, const int* in_sizes, int n_in,
                              void* d_out, int out_size, void* d_ws, size_t ws_size,
                              hipStream_t stream) {
    const float* P = (const float*)d_in[0];
    const float* T = (const float*)d_in[1];
    const int NP = in_sizes[0] / 3;
    const int NT = in_sizes[1] / 3;
    float* out = (float*)d_out;

    unsigned* gminF = (unsigned*)d_ws;
    unsigned* gminB = gminF + NP;
    ushort* Prow = (ushort*)(gminB + NT);
    ushort* Tcol = Prow + (size_t)NP * 16;
    // ws usage: (NP+NT)*4 + (NP+NT)*32 bytes ~= 1.2 MB

    const int eblocks = (NP + NT + TPB - 1) / TPB;
    chamfer_encode<<<eblocks, TPB, 0, stream>>>(P, NP, T, NT, Prow, Tcol, gminF, out);

    dim3 grid((NP + ROWS_PER_BLOCK - 1) / ROWS_PER_BLOCK,
              (NT + CC - 1) / CC, 1);
    chamfer_mfma<<<grid, TPB, 0, stream>>>(Prow, NP, Tcol, NT, gminF, gminB);

    const int fblocks = (NP + NT + TPB - 1) / TPB;
    chamfer_final<<<fblocks, TPB, 0, stream>>>(gminF, NP, gminB, NT,
                                               1.0f / (float)NP, 1.0f / (float)NT, out);
}